// Round 4
// baseline (1163.443 us; speedup 1.0000x reference)
//
#include <hip/hip_runtime.h>

typedef unsigned short u16;
typedef unsigned int   u32;
typedef short bf16x8 __attribute__((ext_vector_type(8)));
typedef float f32x4  __attribute__((ext_vector_type(4)));

__device__ __forceinline__ float bf2f(u16 u){
  union { u32 u; float f; } c; c.u = ((u32)u) << 16; return c.f;
}
__device__ __forceinline__ u16 f2bf(float f){
  union { float f; u32 u; } c; c.f = f;
  u32 u = c.u + 0x7fffu + ((c.u >> 16) & 1u);
  return (u16)(u >> 16);
}

// ---------------- reductions (256 threads = 4 waves) -----------------------
__device__ __forceinline__ float waveRed(float v, int ismax){
  #pragma unroll
  for (int o = 32; o > 0; o >>= 1){
    float t = __shfl_xor(v, o, 64);
    v = ismax ? fmaxf(v, t) : (v + t);
  }
  return v;
}
__device__ __forceinline__ float blockRed(float v, int ismax, float* red, int tid){
  v = waveRed(v, ismax);
  __syncthreads();
  if ((tid & 63) == 0) red[tid >> 6] = v;
  __syncthreads();
  return ismax ? fmaxf(fmaxf(red[0], red[1]), fmaxf(red[2], red[3]))
               : (red[0] + red[1] + red[2] + red[3]);
}

// ---------------- MFMA bf16 GEMM: Y = A(MxK) @ W^T + bias ------------------
// W fp32 row-major NxK, converted to bf16 during LDS staging.
// MODE 0: A fp32, scatter bf16 into (B,nh,S,dk).  MODE 1: A bf16, fp32 out.
// M=8192, N=1024, K=1024. 128x128 tile, BK=32, 256 threads (4 waves, 64x64).
template<int MODE>
__global__ __launch_bounds__(256)
void gemm_bt(const void* __restrict__ Ap, const float* __restrict__ Wm,
             const float* __restrict__ bias, void* __restrict__ outp)
{
  __shared__ u16 As[128][40];      // 32 + 8 pad: rows 80 B apart, conflict-free
  __shared__ u16 Bs[128][40];
  const int tid  = threadIdx.x;
  const int lane = tid & 63;
  const int w    = tid >> 6;
  const int wm = (w >> 1) * 64, wn = (w & 1) * 64;
  const int bm = blockIdx.x, bn = blockIdx.y;

  const f32x4 z = {0.f, 0.f, 0.f, 0.f};
  f32x4 acc[4][4];
  #pragma unroll
  for (int i = 0; i < 4; ++i)
    #pragma unroll
    for (int j = 0; j < 4; ++j) acc[i][j] = z;

  for (int k0 = 0; k0 < 1024; k0 += 32){
    __syncthreads();
    // weights: fp32 -> bf16 into Bs
    #pragma unroll
    for (int c = 0; c < 4; ++c){
      const int idx = tid + c * 256;        // 0..1023 float4-chunks
      const int r   = idx >> 3;             // 0..127
      const int cc  = (idx & 7) * 4;        // 0,4,...,28
      const float4 f = *(const float4*)(Wm + (size_t)(bn * 128 + r) * 1024 + k0 + cc);
      ushort4 o; o.x = f2bf(f.x); o.y = f2bf(f.y); o.z = f2bf(f.z); o.w = f2bf(f.w);
      *(ushort4*)&As[0][0]; // no-op; keep compiler honest
      *(ushort4*)&Bs[r][cc] = o;
    }
    if (MODE == 0){
      const float* Af = (const float*)Ap;
      #pragma unroll
      for (int c = 0; c < 4; ++c){
        const int idx = tid + c * 256;
        const int r   = idx >> 3;
        const int cc  = (idx & 7) * 4;
        const float4 f = *(const float4*)(Af + (size_t)(bm * 128 + r) * 1024 + k0 + cc);
        ushort4 o; o.x = f2bf(f.x); o.y = f2bf(f.y); o.z = f2bf(f.z); o.w = f2bf(f.w);
        *(ushort4*)&As[r][cc] = o;
      }
    } else {
      const u16* Ab = (const u16*)Ap;
      #pragma unroll
      for (int c = 0; c < 2; ++c){
        const int chunk = tid + c * 256;      // 0..511
        const int r  = chunk >> 2;            // 0..127
        const int cc = (chunk & 3) * 8;       // 0,8,16,24
        *(uint4*)&As[r][cc] = *(const uint4*)(Ab + (size_t)(bm * 128 + r) * 1024 + k0 + cc);
      }
    }
    __syncthreads();
    const int fr = lane & 15;
    const int fc = (lane >> 4) * 8;
    bf16x8 af[4], bfv[4];
    #pragma unroll
    for (int i = 0; i < 4; ++i) af[i]  = *(const bf16x8*)&As[wm + i * 16 + fr][fc];
    #pragma unroll
    for (int j = 0; j < 4; ++j) bfv[j] = *(const bf16x8*)&Bs[wn + j * 16 + fr][fc];
    #pragma unroll
    for (int i = 0; i < 4; ++i)
      #pragma unroll
      for (int j = 0; j < 4; ++j)
        acc[i][j] = __builtin_amdgcn_mfma_f32_16x16x32_bf16(af[i], bfv[j], acc[i][j], 0, 0, 0);
  }

  // D layout: row = (lane>>4)*4 + r, col = lane&15 (m89-verified)
  #pragma unroll
  for (int i = 0; i < 4; ++i){
    #pragma unroll
    for (int j = 0; j < 4; ++j){
      const int gr0 = bm * 128 + wm + i * 16 + ((lane >> 4) * 4);
      const int gc  = bn * 128 + wn + j * 16 + (lane & 15);
      const float bvv = bias[gc];
      #pragma unroll
      for (int r = 0; r < 4; ++r){
        const int gr = gr0 + r;
        const float val = acc[i][j][r] + bvv;
        if (MODE == 0){
          const int b = gr >> 8, s = gr & 255, h = gc >> 6, kk = gc & 63;
          ((u16*)outp)[(size_t)b * 262144 + (size_t)h * 16384 + (size_t)s * 64 + kk] = f2bf(val);
        } else {
          ((float*)outp)[(size_t)gr * 1024 + gc] = val;
        }
      }
    }
  }
}

// ---------------- attention: block per (b,s), loop over heads --------------
// Diversity bias inline: for s<64, row s of 1 - softmax(pf[b] @ pf[b]^T), x0.1.
__global__ __launch_bounds__(256)
void attn_kernel(const u16* __restrict__ q, const u16* __restrict__ k,
                 const u16* __restrict__ v, const float* __restrict__ pf,
                 u16* __restrict__ attn_s, float* __restrict__ aw_out)
{
  __shared__ float pfs[64][129];
  __shared__ float qs[64];
  __shared__ float sc[256];
  __shared__ float red[4];
  __shared__ float pv[4][65];
  const int bs = blockIdx.x;            // 8192
  const int b = bs >> 8, s = bs & 255;
  const int tid = threadIdx.x;          // 256
  const int t = tid;

  float dbias = 0.f;
  if (s < 64){                          // block-uniform branch
    const float* pb = pf + (size_t)b * 8192;   // pf[b]: 64x128 fp32
    #pragma unroll
    for (int c = 0; c < 8; ++c){
      const int idx = tid + c * 256;           // 0..2047 float4-chunks
      const float4 f = *(const float4*)(pb + idx * 4);
      float* dst = &pfs[idx >> 5][(idx & 31) * 4];
      dst[0] = f.x; dst[1] = f.y; dst[2] = f.z; dst[3] = f.w;
    }
    __syncthreads();
    if (tid < 64){                      // wave 0 only
      float a = 0.f;
      #pragma unroll 8
      for (int f = 0; f < 128; ++f) a += pfs[s][f] * pfs[tid][f];
      const float m  = waveRed(a, 1);
      const float e  = __expf(a - m);
      const float ss = waveRed(e, 0);
      dbias = 0.1f * (1.f - e / ss);
    }
    __syncthreads();
  }

  float awm = 0.f;
  for (int h = 0; h < 16; ++h){
    const size_t headoff = ((size_t)b * 16 + h) * 16384;
    const u16* kb = k + headoff;
    const u16* vb = v + headoff;
    const u16* qrow = q + headoff + (size_t)s * 64;
    if (tid < 64) qs[tid] = bf2f(qrow[tid]);
    __syncthreads();

    float acc = 0.f;
    const u16* kr = kb + (size_t)t * 64;
    #pragma unroll
    for (int c = 0; c < 8; ++c){
      const uint4 p = *(const uint4*)(kr + c * 8);
      float kf[8];
      kf[0] = bf2f((u16)(p.x & 0xffffu)); kf[1] = bf2f((u16)(p.x >> 16));
      kf[2] = bf2f((u16)(p.y & 0xffffu)); kf[3] = bf2f((u16)(p.y >> 16));
      kf[4] = bf2f((u16)(p.z & 0xffffu)); kf[5] = bf2f((u16)(p.z >> 16));
      kf[6] = bf2f((u16)(p.w & 0xffffu)); kf[7] = bf2f((u16)(p.w >> 16));
      #pragma unroll
      for (int j = 0; j < 8; ++j) acc += qs[c * 8 + j] * kf[j];
    }
    const float score = acc * 0.125f;

    // softmax WITHOUT bias (attention_weights, mean over heads)
    const float m1 = blockRed(score, 1, red, tid);
    const float e1 = __expf(score - m1);
    const float s1 = blockRed(e1, 0, red, tid);
    awm += e1 / s1;

    // softmax WITH diversity bias (drives PV)
    const float sb = score + dbias;
    const float m2 = blockRed(sb, 1, red, tid);
    const float e2 = __expf(sb - m2);
    const float s2 = blockRed(e2, 0, red, tid);
    sc[t] = e2 / s2;
    __syncthreads();

    const int kk = tid & 63, part = tid >> 6;
    float pacc = 0.f;
    const u16* vp = vb + (size_t)part * 64 * 64 + kk;
    #pragma unroll 8
    for (int tt = 0; tt < 64; ++tt)
      pacc += sc[part * 64 + tt] * bf2f(vp[(size_t)tt * 64]);
    pv[part][kk] = pacc;
    __syncthreads();
    if (tid < 64){
      const float val = pv[0][tid] + pv[1][tid] + pv[2][tid] + pv[3][tid];
      // torch-faithful scramble of transpose(1,2).view(B,S,d)
      const int bp = 2 * h + (b >> 4);
      const int sp = (b & 15) * 16 + (s >> 4);
      const int cp = (s & 15) * 64 + tid;
      attn_s[((size_t)bp * 256 + sp) * 1024 + cp] = f2bf(val);
    }
    __syncthreads();
  }
  aw_out[(size_t)bs * 256 + t] = awm * 0.0625f;
}

// ---------------- residual + layernorm epilogue (all fp32) -----------------
__global__ __launch_bounds__(256)
void ln_kernel(const float* __restrict__ y2, const float* __restrict__ x,
               const float* __restrict__ g, const float* __restrict__ bb,
               float* __restrict__ outp)
{
  __shared__ float red[4];
  const int r = blockIdx.x, tid = threadIdx.x;
  const float4 yv = ((const float4*)(y2 + (size_t)r * 1024))[tid];
  const float4 xv = ((const float4*)(x  + (size_t)r * 1024))[tid];
  const float v0 = yv.x + xv.x;
  const float v1 = yv.y + xv.y;
  const float v2 = yv.z + xv.z;
  const float v3 = yv.w + xv.w;
  const float ssum = blockRed(v0 + v1 + v2 + v3, 0, red, tid);
  const float mu = ssum * (1.f / 1024.f);
  const float d0 = v0 - mu, d1 = v1 - mu, d2 = v2 - mu, d3 = v3 - mu;
  const float sq = blockRed(d0 * d0 + d1 * d1 + d2 * d2 + d3 * d3, 0, red, tid);
  const float rstd = rsqrtf(sq * (1.f / 1024.f) + 1e-5f);
  const float4 gv = ((const float4*)g)[tid];
  const float4 bv = ((const float4*)bb)[tid];
  float4 o;
  o.x = d0 * rstd * gv.x + bv.x;
  o.y = d1 * rstd * gv.y + bv.y;
  o.z = d2 * rstd * gv.z + bv.z;
  o.w = d3 * rstd * gv.w + bv.w;
  ((float4*)(outp + (size_t)r * 1024))[tid] = o;
}

extern "C" void kernel_launch(void* const* d_in, const int* in_sizes, int n_in,
                              void* d_out, int out_size, void* d_ws, size_t ws_size,
                              hipStream_t stream)
{
  // identify inputs by size signature (robust; resolves same as positional)
  int ix = -1, ipf = -1, iw[4] = {-1,-1,-1,-1}, iv[6] = {-1,-1,-1,-1,-1,-1};
  int nw = 0, nv = 0;
  for (int i = 0; i < n_in; ++i){
    const int sz = in_sizes[i];
    if (sz == 8388608 && ix < 0) ix = i;
    else if (sz == 262144 && ipf < 0) ipf = i;
    else if (sz == 1048576 && nw < 4) iw[nw++] = i;
    else if (sz == 1024 && nv < 6) iv[nv++] = i;
  }
  if (ix < 0 || ipf < 0 || nw != 4 || nv != 6){
    ix = 0; ipf = 1; iw[0] = 2; iv[0] = 3; iw[1] = 4; iv[1] = 5;
    iw[2] = 6; iv[2] = 7; iw[3] = 8; iv[3] = 9; iv[4] = 10; iv[5] = 11;
  }

  const float* x   = (const float*)d_in[ix];
  const float* pf  = (const float*)d_in[ipf];
  const float* wq  = (const float*)d_in[iw[0]];
  const float* wk  = (const float*)d_in[iw[1]];
  const float* wv  = (const float*)d_in[iw[2]];
  const float* wo  = (const float*)d_in[iw[3]];
  const float* bq  = (const float*)d_in[iv[0]];
  const float* bk  = (const float*)d_in[iv[1]];
  const float* bv  = (const float*)d_in[iv[2]];
  const float* bo  = (const float*)d_in[iv[3]];
  const float* lng = (const float*)d_in[iv[4]];
  const float* lnb = (const float*)d_in[iv[5]];

  float* out0   = (float*)d_out;            // (B,H,W,d) fp32
  float* aw_out = out0 + 8388608;           // (B,S,S) fp32

  // ws (48 MiB): qw [0,16M) kw [16M,32M) vw [32M,48M) bf16;
  // y2 fp32 (32 MiB) aliases qw+kw after attention.
  // attn bf16 scratch (16.8 MB) lives in out0's fp32 region (33.5 MB) until
  // ln_kernel overwrites it (stream-sequential).
  u16* qw   = (u16*)d_ws;
  u16* kw   = qw + 8388608;
  u16* vw   = kw + 8388608;
  float* y2 = (float*)d_ws;
  u16* attn = (u16*)d_out;

  const dim3 gg(64, 8);
  gemm_bt<0><<<gg, 256, 0, stream>>>(x, wq, bq, (void*)qw);
  gemm_bt<0><<<gg, 256, 0, stream>>>(x, wk, bk, (void*)kw);
  gemm_bt<0><<<gg, 256, 0, stream>>>(x, wv, bv, (void*)vw);

  attn_kernel<<<8192, 256, 0, stream>>>(qw, kw, vw, pf, attn, aw_out);

  gemm_bt<1><<<gg, 256, 0, stream>>>(attn, wo, bo, (void*)y2);
  ln_kernel<<<8192, 256, 0, stream>>>(y2, x, lng, lnb, out0);
}

// Round 5
// 413.653 us; speedup vs baseline: 2.8126x; 2.8126x over previous
//
#include <hip/hip_runtime.h>

typedef unsigned short u16;
typedef unsigned int   u32;
typedef short bf16x8 __attribute__((ext_vector_type(8)));
typedef float f32x4  __attribute__((ext_vector_type(4)));

__device__ __forceinline__ float bf2f(u16 u){
  union { u32 u; float f; } c; c.u = ((u32)u) << 16; return c.f;
}
__device__ __forceinline__ u16 f2bf(float f){
  union { float f; u32 u; } c; c.f = f;
  u32 u = c.u + 0x7fffu + ((c.u >> 16) & 1u);
  return (u16)(u >> 16);
}

// ---------------- reductions ----------------------------------------------
__device__ __forceinline__ float waveRed(float v, int ismax){
  #pragma unroll
  for (int o = 32; o > 0; o >>= 1){
    float t = __shfl_xor(v, o, 64);
    v = ismax ? fmaxf(v, t) : (v + t);
  }
  return v;
}
__device__ __forceinline__ float blockRed(float v, int ismax, float* red, int tid){
  v = waveRed(v, ismax);
  __syncthreads();
  if ((tid & 63) == 0) red[tid >> 6] = v;
  __syncthreads();
  return ismax ? fmaxf(fmaxf(red[0], red[1]), fmaxf(red[2], red[3]))
               : (red[0] + red[1] + red[2] + red[3]);
}

// ---------------- diversity bias table: divp[b][s][t] ----------------------
__global__ __launch_bounds__(256)
void div_kernel(const float* __restrict__ pf, float* __restrict__ divp)
{
  __shared__ float pfs[64][129];   // stride 129: (lane + f) % 32 -> 2/bank, free
  __shared__ float svs[64][65];
  const int b = blockIdx.x;
  const int tid = threadIdx.x;
  const float* pb = pf + (size_t)b * 8192;
  for (int i = tid; i < 8192; i += 256) pfs[i >> 7][i & 127] = pb[i];
  __syncthreads();
  const int p = tid & 63, qg = tid >> 6;       // 4 q-groups of 16
  for (int qq = qg * 16; qq < qg * 16 + 16; ++qq){
    float a = 0.f;
    #pragma unroll 8
    for (int f = 0; f < 128; ++f) a += pfs[p][f] * pfs[qq][f];
    svs[p][qq] = a;
  }
  __syncthreads();
  if (tid < 64){
    float m = -1e30f;
    for (int qq = 0; qq < 64; ++qq) m = fmaxf(m, svs[tid][qq]);
    float s = 0.f;
    for (int qq = 0; qq < 64; ++qq){ const float e = __expf(svs[tid][qq] - m); svs[tid][qq] = e; s += e; }
    const float inv = 1.f / s;
    float* dr = divp + ((size_t)b * 64 + tid) * 64;
    for (int qq = 0; qq < 64; ++qq) dr[qq] = 0.1f * (1.f - svs[tid][qq] * inv);
  }
}

// ---------------- MFMA bf16 GEMM: Y = (A @ W^T + bias) * scale -------------
// W fp32 row-major NxK -> bf16 during staging. M=8192, N=K=1024.
// MODE 0: A fp32, scatter bf16 into (B,nh,S,dk).  MODE 1: A bf16, fp32 out.
template<int MODE>
__global__ __launch_bounds__(256)
void gemm_bt(const void* __restrict__ Ap, const float* __restrict__ Wm,
             const float* __restrict__ bias, void* __restrict__ outp, float scale)
{
  __shared__ u16 As[128][40];
  __shared__ u16 Bs[128][40];
  const int tid  = threadIdx.x;
  const int lane = tid & 63;
  const int w    = tid >> 6;
  const int wm = (w >> 1) * 64, wn = (w & 1) * 64;
  const int bm = blockIdx.x, bn = blockIdx.y;

  const f32x4 z = {0.f, 0.f, 0.f, 0.f};
  f32x4 acc[4][4];
  #pragma unroll
  for (int i = 0; i < 4; ++i)
    #pragma unroll
    for (int j = 0; j < 4; ++j) acc[i][j] = z;

  for (int k0 = 0; k0 < 1024; k0 += 32){
    __syncthreads();
    #pragma unroll
    for (int c = 0; c < 4; ++c){
      const int idx = tid + c * 256;
      const int r   = idx >> 3;
      const int cc  = (idx & 7) * 4;
      const float4 f = *(const float4*)(Wm + (size_t)(bn * 128 + r) * 1024 + k0 + cc);
      ushort4 o; o.x = f2bf(f.x); o.y = f2bf(f.y); o.z = f2bf(f.z); o.w = f2bf(f.w);
      *(ushort4*)&Bs[r][cc] = o;
    }
    if (MODE == 0){
      const float* Af = (const float*)Ap;
      #pragma unroll
      for (int c = 0; c < 4; ++c){
        const int idx = tid + c * 256;
        const int r   = idx >> 3;
        const int cc  = (idx & 7) * 4;
        const float4 f = *(const float4*)(Af + (size_t)(bm * 128 + r) * 1024 + k0 + cc);
        ushort4 o; o.x = f2bf(f.x); o.y = f2bf(f.y); o.z = f2bf(f.z); o.w = f2bf(f.w);
        *(ushort4*)&As[r][cc] = o;
      }
    } else {
      const u16* Ab = (const u16*)Ap;
      #pragma unroll
      for (int c = 0; c < 2; ++c){
        const int chunk = tid + c * 256;
        const int r  = chunk >> 2;
        const int cc = (chunk & 3) * 8;
        *(uint4*)&As[r][cc] = *(const uint4*)(Ab + (size_t)(bm * 128 + r) * 1024 + k0 + cc);
      }
    }
    __syncthreads();
    const int fr = lane & 15;
    const int fc = (lane >> 4) * 8;
    bf16x8 af[4], bfv[4];
    #pragma unroll
    for (int i = 0; i < 4; ++i) af[i]  = *(const bf16x8*)&As[wm + i * 16 + fr][fc];
    #pragma unroll
    for (int j = 0; j < 4; ++j) bfv[j] = *(const bf16x8*)&Bs[wn + j * 16 + fr][fc];
    #pragma unroll
    for (int i = 0; i < 4; ++i)
      #pragma unroll
      for (int j = 0; j < 4; ++j)
        acc[i][j] = __builtin_amdgcn_mfma_f32_16x16x32_bf16(af[i], bfv[j], acc[i][j], 0, 0, 0);
  }

  // D layout: row = (lane>>4)*4 + r, col = lane&15 (m89-verified)
  #pragma unroll
  for (int i = 0; i < 4; ++i){
    #pragma unroll
    for (int j = 0; j < 4; ++j){
      const int gr0 = bm * 128 + wm + i * 16 + ((lane >> 4) * 4);
      const int gc  = bn * 128 + wn + j * 16 + (lane & 15);
      const float bvv = bias[gc];
      #pragma unroll
      for (int r = 0; r < 4; ++r){
        const int gr = gr0 + r;
        const float val = (acc[i][j][r] + bvv) * scale;
        if (MODE == 0){
          const int b = gr >> 8, s = gr & 255, h = gc >> 6, kk = gc & 63;
          ((u16*)outp)[(size_t)b * 262144 + (size_t)h * 16384 + (size_t)s * 64 + kk] = f2bf(val);
        } else {
          ((float*)outp)[(size_t)gr * 1024 + gc] = val;
        }
      }
    }
  }
}

// ---------------- MFMA attention: block per (b,h) --------------------------
// q is pre-scaled by 1/8 in the Q projection. Scores = q@k^T (MFMA).
// Softmax in-register (C-layout rows span 16 lanes). P->A-layout via per-wave
// LDS strip (two 128-col halves). PV against LDS-transposed V.
__global__ __launch_bounds__(256)
void attn_mfma(const u16* __restrict__ q, const u16* __restrict__ k,
               const u16* __restrict__ v, const float* __restrict__ divp,
               u16* __restrict__ attn_s)
{
  __shared__ u16 Vt[64][264];        // V^T: Vt[n][t]; stride 264 -> aligned+floor
  __shared__ u16 Ps[4][16][136];     // per-wave P strip, 128 cols + 8 pad
  const int bh = blockIdx.x;
  const int b = bh >> 4, h = bh & 15;
  const int tid = threadIdx.x, lane = tid & 63, w = tid >> 6;
  const int quad = lane >> 4, l15 = lane & 15;
  const u16* kh = k + (size_t)bh * 16384;
  const u16* vh = v + (size_t)bh * 16384;
  const u16* qh = q + (size_t)bh * 16384;

  // stage V transposed: pack row pairs (2t,2t+1) into b32 writes
  #pragma unroll
  for (int c = 0; c < 4; ++c){
    const int pidx = tid + c * 256;          // 0..1023
    const int t2 = pidx & 127;               // row pair (2t2, 2t2+1)
    const int n0 = (pidx >> 7) * 8;          // 0,8,..,56
    const uint4 a  = *(const uint4*)(vh + (2 * t2) * 64 + n0);
    const uint4 bb = *(const uint4*)(vh + (2 * t2 + 1) * 64 + n0);
    const u32 aa[4] = {a.x, a.y, a.z, a.w};
    const u32 bb4[4] = {bb.x, bb.y, bb.z, bb.w};
    #pragma unroll
    for (int j2 = 0; j2 < 4; ++j2){
      const u32 lo = aa[j2], hi = bb4[j2];
      *(u32*)&Vt[n0 + 2 * j2    ][2 * t2] = (lo & 0xffffu) | (hi << 16);
      *(u32*)&Vt[n0 + 2 * j2 + 1][2 * t2] = (lo >> 16) | (hi & 0xffff0000u);
    }
  }
  __syncthreads();

  const f32x4 z = {0.f, 0.f, 0.f, 0.f};
  const int bp = 2 * h + (b >> 4);
  for (int i = 0; i < 4; ++i){               // 16-row strips
    const int row0 = w * 64 + i * 16;
    const bf16x8 af0 = *(const bf16x8*)(qh + (size_t)(row0 + l15) * 64 + quad * 8);
    const bf16x8 af1 = *(const bf16x8*)(qh + (size_t)(row0 + l15) * 64 + 32 + quad * 8);
    f32x4 sc[16];
    #pragma unroll
    for (int ct = 0; ct < 16; ++ct){
      const bf16x8 b0 = *(const bf16x8*)(kh + (size_t)(ct * 16 + l15) * 64 + quad * 8);
      const bf16x8 b1 = *(const bf16x8*)(kh + (size_t)(ct * 16 + l15) * 64 + 32 + quad * 8);
      f32x4 a = __builtin_amdgcn_mfma_f32_16x16x32_bf16(af0, b0, z, 0, 0, 0);
      sc[ct]  = __builtin_amdgcn_mfma_f32_16x16x32_bf16(af1, b1, a, 0, 0, 0);
    }
    // diversity bias: rows<64 == wave 0; cols<64 == ct<4
    if (w == 0){
      const float* dv = divp + (size_t)b * 4096 + (size_t)(i * 16 + quad * 4) * 64 + l15;
      #pragma unroll
      for (int ct = 0; ct < 4; ++ct)
        #pragma unroll
        for (int rr = 0; rr < 4; ++rr)
          sc[ct][rr] += dv[rr * 64 + ct * 16];
    }
    // softmax: row = quad*4+rr held across 16 lanes (same quad)
    float rs[4];
    #pragma unroll
    for (int rr = 0; rr < 4; ++rr){
      float m = sc[0][rr];
      #pragma unroll
      for (int ct = 1; ct < 16; ++ct) m = fmaxf(m, sc[ct][rr]);
      #pragma unroll
      for (int o = 1; o < 16; o <<= 1) m = fmaxf(m, __shfl_xor(m, o, 64));
      float s = 0.f;
      #pragma unroll
      for (int ct = 0; ct < 16; ++ct){
        const float e = __expf(sc[ct][rr] - m); sc[ct][rr] = e; s += e;
      }
      #pragma unroll
      for (int o = 1; o < 16; o <<= 1) s += __shfl_xor(s, o, 64);
      rs[rr] = 1.f / s;
    }
    // PV in two 128-col halves through the per-wave Ps strip
    f32x4 o4[4] = {z, z, z, z};
    #pragma unroll
    for (int half = 0; half < 2; ++half){
      #pragma unroll
      for (int ct = 0; ct < 8; ++ct)
        #pragma unroll
        for (int rr = 0; rr < 4; ++rr)
          Ps[w][quad * 4 + rr][ct * 16 + l15] = f2bf(sc[half * 8 + ct][rr] * rs[rr]);
      // same-wave ds_write->ds_read: compiler inserts lgkmcnt wait
      #pragma unroll
      for (int kc = 0; kc < 4; ++kc){
        const bf16x8 pa = *(const bf16x8*)&Ps[w][l15][kc * 32 + quad * 8];
        #pragma unroll
        for (int nt = 0; nt < 4; ++nt){
          const bf16x8 vb8 = *(const bf16x8*)&Vt[nt * 16 + l15][half * 128 + kc * 32 + quad * 8];
          o4[nt] = __builtin_amdgcn_mfma_f32_16x16x32_bf16(pa, vb8, o4[nt], 0, 0, 0);
        }
      }
    }
    // torch-faithful scramble store of transpose(1,2).view(B,S,d)
    const int sp = (b & 15) * 16 + (w * 4 + i);     // s>>4 == w*4+i
    #pragma unroll
    for (int nt = 0; nt < 4; ++nt)
      #pragma unroll
      for (int rr = 0; rr < 4; ++rr){
        const int slo = quad * 4 + rr;              // s & 15
        const int cp = slo * 64 + nt * 16 + l15;
        attn_s[((size_t)bp * 256 + sp) * 1024 + cp] = f2bf(o4[nt][rr]);
      }
  }
}

// ---------------- attention_weights: mean over heads of softmax(scores) ----
// Block per (b, 16-row strip) = 512 blocks; 4 waves split 256 cols 4-way.
__global__ __launch_bounds__(256)
void aw_kernel(const u16* __restrict__ q, const u16* __restrict__ k,
               float* __restrict__ aw)
{
  __shared__ float redm[16][4];
  __shared__ float reds[16][4];
  const int blk = blockIdx.x;
  const int b = blk >> 4, st = blk & 15;
  const int tid = threadIdx.x, lane = tid & 63, w = tid >> 6;
  const int quad = lane >> 4, l15 = lane & 15;
  const int rowb = st * 16;
  const f32x4 z = {0.f, 0.f, 0.f, 0.f};
  float awacc[4][4] = {};
  for (int h = 0; h < 16; ++h){
    const u16* kh = k + (((size_t)b * 16 + h) * 16384);
    const u16* qh = q + (((size_t)b * 16 + h) * 16384);
    const bf16x8 af0 = *(const bf16x8*)(qh + (size_t)(rowb + l15) * 64 + quad * 8);
    const bf16x8 af1 = *(const bf16x8*)(qh + (size_t)(rowb + l15) * 64 + 32 + quad * 8);
    f32x4 sc[4];
    #pragma unroll
    for (int j4 = 0; j4 < 4; ++j4){
      const int ct = w * 4 + j4;
      const bf16x8 b0 = *(const bf16x8*)(kh + (size_t)(ct * 16 + l15) * 64 + quad * 8);
      const bf16x8 b1 = *(const bf16x8*)(kh + (size_t)(ct * 16 + l15) * 64 + 32 + quad * 8);
      f32x4 a = __builtin_amdgcn_mfma_f32_16x16x32_bf16(af0, b0, z, 0, 0, 0);
      sc[j4]  = __builtin_amdgcn_mfma_f32_16x16x32_bf16(af1, b1, a, 0, 0, 0);
    }
    float pm[4];
    #pragma unroll
    for (int rr = 0; rr < 4; ++rr){
      float m = fmaxf(fmaxf(sc[0][rr], sc[1][rr]), fmaxf(sc[2][rr], sc[3][rr]));
      #pragma unroll
      for (int o = 1; o < 16; o <<= 1) m = fmaxf(m, __shfl_xor(m, o, 64));
      pm[rr] = m;
    }
    if (l15 == 0)
      #pragma unroll
      for (int rr = 0; rr < 4; ++rr) redm[quad * 4 + rr][w] = pm[rr];
    __syncthreads();
    float ps[4];
    #pragma unroll
    for (int rr = 0; rr < 4; ++rr){
      const int row = quad * 4 + rr;
      const float m = fmaxf(fmaxf(redm[row][0], redm[row][1]),
                            fmaxf(redm[row][2], redm[row][3]));
      float s = 0.f;
      #pragma unroll
      for (int j4 = 0; j4 < 4; ++j4){
        const float e = __expf(sc[j4][rr] - m); sc[j4][rr] = e; s += e;
      }
      #pragma unroll
      for (int o = 1; o < 16; o <<= 1) s += __shfl_xor(s, o, 64);
      ps[rr] = s;
    }
    if (l15 == 0)
      #pragma unroll
      for (int rr = 0; rr < 4; ++rr) reds[quad * 4 + rr][w] = ps[rr];
    __syncthreads();
    #pragma unroll
    for (int rr = 0; rr < 4; ++rr){
      const int row = quad * 4 + rr;
      const float inv = 1.f / (reds[row][0] + reds[row][1] + reds[row][2] + reds[row][3]);
      #pragma unroll
      for (int j4 = 0; j4 < 4; ++j4) awacc[j4][rr] += sc[j4][rr] * inv;
    }
  }
  const size_t base = (size_t)b * 65536;
  #pragma unroll
  for (int j4 = 0; j4 < 4; ++j4){
    const int col = (w * 4 + j4) * 16 + l15;
    #pragma unroll
    for (int rr = 0; rr < 4; ++rr){
      const int row = rowb + quad * 4 + rr;
      aw[base + (size_t)row * 256 + col] = awacc[j4][rr] * 0.0625f;
    }
  }
}

// ---------------- residual + layernorm epilogue (fp32) ---------------------
__global__ __launch_bounds__(256)
void ln_kernel(const float* __restrict__ y2, const float* __restrict__ x,
               const float* __restrict__ g, const float* __restrict__ bb,
               float* __restrict__ outp)
{
  __shared__ float red[4];
  const int r = blockIdx.x, tid = threadIdx.x;
  const float4 yv = ((const float4*)(y2 + (size_t)r * 1024))[tid];
  const float4 xv = ((const float4*)(x  + (size_t)r * 1024))[tid];
  const float v0 = yv.x + xv.x;
  const float v1 = yv.y + xv.y;
  const float v2 = yv.z + xv.z;
  const float v3 = yv.w + xv.w;
  const float ssum = blockRed(v0 + v1 + v2 + v3, 0, red, tid);
  const float mu = ssum * (1.f / 1024.f);
  const float d0 = v0 - mu, d1 = v1 - mu, d2 = v2 - mu, d3 = v3 - mu;
  const float sq = blockRed(d0 * d0 + d1 * d1 + d2 * d2 + d3 * d3, 0, red, tid);
  const float rstd = rsqrtf(sq * (1.f / 1024.f) + 1e-5f);
  const float4 gv = ((const float4*)g)[tid];
  const float4 bv = ((const float4*)bb)[tid];
  float4 o;
  o.x = d0 * rstd * gv.x + bv.x;
  o.y = d1 * rstd * gv.y + bv.y;
  o.z = d2 * rstd * gv.z + bv.z;
  o.w = d3 * rstd * gv.w + bv.w;
  ((float4*)(outp + (size_t)r * 1024))[tid] = o;
}

extern "C" void kernel_launch(void* const* d_in, const int* in_sizes, int n_in,
                              void* d_out, int out_size, void* d_ws, size_t ws_size,
                              hipStream_t stream)
{
  int ix = -1, ipf = -1, iw[4] = {-1,-1,-1,-1}, iv[6] = {-1,-1,-1,-1,-1,-1};
  int nw = 0, nv = 0;
  for (int i = 0; i < n_in; ++i){
    const int sz = in_sizes[i];
    if (sz == 8388608 && ix < 0) ix = i;
    else if (sz == 262144 && ipf < 0) ipf = i;
    else if (sz == 1048576 && nw < 4) iw[nw++] = i;
    else if (sz == 1024 && nv < 6) iv[nv++] = i;
  }
  if (ix < 0 || ipf < 0 || nw != 4 || nv != 6){
    ix = 0; ipf = 1; iw[0] = 2; iv[0] = 3; iw[1] = 4; iv[1] = 5;
    iw[2] = 6; iv[2] = 7; iw[3] = 8; iv[3] = 9; iv[4] = 10; iv[5] = 11;
  }

  const float* x   = (const float*)d_in[ix];
  const float* pf  = (const float*)d_in[ipf];
  const float* wq  = (const float*)d_in[iw[0]];
  const float* wk  = (const float*)d_in[iw[1]];
  const float* wv  = (const float*)d_in[iw[2]];
  const float* wo  = (const float*)d_in[iw[3]];
  const float* bq  = (const float*)d_in[iv[0]];
  const float* bk  = (const float*)d_in[iv[1]];
  const float* bv  = (const float*)d_in[iv[2]];
  const float* bo  = (const float*)d_in[iv[3]];
  const float* lng = (const float*)d_in[iv[4]];
  const float* lnb = (const float*)d_in[iv[5]];

  float* out0   = (float*)d_out;            // (B,H,W,d) fp32, 33.5 MB
  float* aw_out = out0 + 8388608;           // (B,S,S) fp32, 8.4 MB

  // ws: qw [0,16M) kw [16M,32M) vw [32M,48M) bf16; divp fp32 @48M (512 KB);
  // y2 fp32 (32 MB) aliases qw+kw after attention+aw are done.
  // attn bf16 scratch (16.8 MB) lives in out0's region until ln overwrites it.
  u16* qw   = (u16*)d_ws;
  u16* kw   = qw + 8388608;
  u16* vw   = kw + 8388608;
  float* divp = (float*)((char*)d_ws + (size_t)48 * 1048576);
  float* y2 = (float*)d_ws;
  u16* attn = (u16*)d_out;

  div_kernel<<<32, 256, 0, stream>>>(pf, divp);

  const dim3 gg(64, 8);
  gemm_bt<0><<<gg, 256, 0, stream>>>(x, wq, bq, (void*)qw, 0.125f);  // fold 1/sqrt(dk)
  gemm_bt<0><<<gg, 256, 0, stream>>>(x, wk, bk, (void*)kw, 1.0f);
  gemm_bt<0><<<gg, 256, 0, stream>>>(x, wv, bv, (void*)vw, 1.0f);

  attn_mfma<<<512, 256, 0, stream>>>(qw, kw, vw, divp, attn);
  aw_kernel<<<512, 256, 0, stream>>>(qw, kw, aw_out);

  gemm_bt<1><<<gg, 256, 0, stream>>>(attn, wo, bo, (void*)y2, 1.0f);
  ln_kernel<<<8192, 256, 0, stream>>>(y2, x, lng, lnb, out0);
}

// Round 6
// 330.774 us; speedup vs baseline: 3.5173x; 1.2506x over previous
//
#include <hip/hip_runtime.h>

typedef unsigned short u16;
typedef unsigned int   u32;
typedef short bf16x8 __attribute__((ext_vector_type(8)));
typedef float f32x4  __attribute__((ext_vector_type(4)));

__device__ __forceinline__ float bf2f(u16 u){
  union { u32 u; float f; } c; c.u = ((u32)u) << 16; return c.f;
}
__device__ __forceinline__ u16 f2bf(float f){
  union { float f; u32 u; } c; c.f = f;
  u32 u = c.u + 0x7fffu + ((c.u >> 16) & 1u);
  return (u16)(u >> 16);
}

// async global->LDS, 16B per lane; LDS dest must be wave-uniform base + lane*16
__device__ __forceinline__ void gload16(const u16* g, u16* l){
  __builtin_amdgcn_global_load_lds((const __attribute__((address_space(1))) u32*)g,
                                   (__attribute__((address_space(3))) u32*)l, 16, 0, 0);
}

// ---------------- reductions ----------------------------------------------
__device__ __forceinline__ float waveRed(float v, int ismax){
  #pragma unroll
  for (int o = 32; o > 0; o >>= 1){
    float t = __shfl_xor(v, o, 64);
    v = ismax ? fmaxf(v, t) : (v + t);
  }
  return v;
}
__device__ __forceinline__ float blockRed(float v, int ismax, float* red, int tid){
  v = waveRed(v, ismax);
  __syncthreads();
  if ((tid & 63) == 0) red[tid >> 6] = v;
  __syncthreads();
  return ismax ? fmaxf(fmaxf(red[0], red[1]), fmaxf(red[2], red[3]))
               : (red[0] + red[1] + red[2] + red[3]);
}

// ---------------- fp32 -> bf16 converters ----------------------------------
__global__ __launch_bounds__(256)
void conv_x(const float* __restrict__ src, u16* __restrict__ dst){
  const size_t i = ((size_t)blockIdx.x * 256 + threadIdx.x) * 8;
  const float4 a = *(const float4*)(src + i);
  const float4 b = *(const float4*)(src + i + 4);
  uint4 o;
  o.x = (u32)f2bf(a.x) | ((u32)f2bf(a.y) << 16);
  o.y = (u32)f2bf(a.z) | ((u32)f2bf(a.w) << 16);
  o.z = (u32)f2bf(b.x) | ((u32)f2bf(b.y) << 16);
  o.w = (u32)f2bf(b.z) | ((u32)f2bf(b.w) << 16);
  *(uint4*)(dst + i) = o;
}

__global__ __launch_bounds__(256)
void conv_w4(const float* __restrict__ w0, const float* __restrict__ w1,
             const float* __restrict__ w2, const float* __restrict__ w3,
             u16* __restrict__ dst){
  const float* s = blockIdx.y == 0 ? w0 : (blockIdx.y == 1 ? w1 : (blockIdx.y == 2 ? w2 : w3));
  u16* d = dst + (size_t)blockIdx.y * 1048576;
  const size_t i = ((size_t)blockIdx.x * 256 + threadIdx.x) * 8;   // 512 blocks
  const float4 a = *(const float4*)(s + i);
  const float4 b = *(const float4*)(s + i + 4);
  uint4 o;
  o.x = (u32)f2bf(a.x) | ((u32)f2bf(a.y) << 16);
  o.y = (u32)f2bf(a.z) | ((u32)f2bf(a.w) << 16);
  o.z = (u32)f2bf(b.x) | ((u32)f2bf(b.y) << 16);
  o.w = (u32)f2bf(b.z) | ((u32)f2bf(b.w) << 16);
  *(uint4*)(d + i) = o;
}

// ---------------- diversity bias table: divp[b][s][t] ----------------------
__global__ __launch_bounds__(256)
void div_kernel(const float* __restrict__ pf, float* __restrict__ divp)
{
  __shared__ float pfs[64][129];
  __shared__ float svs[64][65];
  const int b = blockIdx.x;
  const int tid = threadIdx.x;
  const float* pb = pf + (size_t)b * 8192;
  for (int i = tid; i < 8192; i += 256) pfs[i >> 7][i & 127] = pb[i];
  __syncthreads();
  const int p = tid & 63, qg = tid >> 6;
  for (int qq = qg * 16; qq < qg * 16 + 16; ++qq){
    float a = 0.f;
    #pragma unroll 8
    for (int f = 0; f < 128; ++f) a += pfs[p][f] * pfs[qq][f];
    svs[p][qq] = a;
  }
  __syncthreads();
  if (tid < 64){
    float m = -1e30f;
    for (int qq = 0; qq < 64; ++qq) m = fmaxf(m, svs[tid][qq]);
    float s = 0.f;
    for (int qq = 0; qq < 64; ++qq){ const float e = __expf(svs[tid][qq] - m); svs[tid][qq] = e; s += e; }
    const float inv = 1.f / s;
    float* dr = divp + ((size_t)b * 64 + tid) * 64;
    for (int qq = 0; qq < 64; ++qq) dr[qq] = 0.1f * (1.f - svs[tid][qq] * inv);
  }
}

// ---------------- m97-style MFMA GEMM: Y = (A @ W^T + bias) * scale --------
// A,W bf16 K-contiguous (K=1024). 128x128 tile, BK=32, global_load_lds 16B.
// MODE 0: fused QKV (grid y 0..23, wsel = y>>3), scatter bf16 (B,nh,S,dk).
// MODE 1: out-proj, fp32 row-major out.
template<int MODE>
__global__ __launch_bounds__(256)
void gemm_lds(const u16* __restrict__ A, const u16* __restrict__ Wb,
              const float* __restrict__ bias0, const float* __restrict__ bias1,
              const float* __restrict__ bias2, void* __restrict__ outp)
{
  __shared__ u16 As[128 * 32];     // row-major [128][32], NO pad (glld layout)
  __shared__ u16 Bs[128 * 32];
  const int tid = threadIdx.x, lane = tid & 63, w = tid >> 6;
  const int wm = (w >> 1) * 64, wn = (w & 1) * 64;
  const int bm = blockIdx.x;
  int bn = blockIdx.y;
  const u16* Wp = Wb;
  const float* bias = bias0;
  float scale = 1.f;
  int wsel = 0;
  if (MODE == 0){
    wsel = bn >> 3; bn &= 7;
    Wp = Wb + (size_t)wsel * 1048576;
    bias = wsel == 0 ? bias0 : (wsel == 1 ? bias1 : bias2);
    if (wsel == 0) scale = 0.125f;      // fold 1/sqrt(dk) into Q
  }

  const f32x4 z = {0.f, 0.f, 0.f, 0.f};
  f32x4 acc[4][4];
  #pragma unroll
  for (int i = 0; i < 4; ++i)
    #pragma unroll
    for (int j = 0; j < 4; ++j) acc[i][j] = z;

  // staging: 8 chunks of 1KB per tile; wave w owns chunks w*2, w*2+1.
  // chunk ca covers rows [ca*16, ca*16+16); lane i -> row +i/4, col (i&3)*8.
  const int r4 = lane >> 2, c8 = (lane & 3) * 8;
  const int ca0 = w * 2, ca1 = w * 2 + 1;
  const u16* ga0 = A  + (size_t)(bm * 128 + ca0 * 16 + r4) * 1024 + c8;
  const u16* ga1 = A  + (size_t)(bm * 128 + ca1 * 16 + r4) * 1024 + c8;
  const u16* gb0 = Wp + (size_t)(bn * 128 + ca0 * 16 + r4) * 1024 + c8;
  const u16* gb1 = Wp + (size_t)(bn * 128 + ca1 * 16 + r4) * 1024 + c8;
  u16* la0 = As + ca0 * 512 + lane * 8;
  u16* la1 = As + ca1 * 512 + lane * 8;
  u16* lb0 = Bs + ca0 * 512 + lane * 8;
  u16* lb1 = Bs + ca1 * 512 + lane * 8;

  const int fr = lane & 15, q8 = (lane >> 4) * 8;
  for (int k0 = 0; k0 < 1024; k0 += 32){
    __syncthreads();                 // prev iter frag reads done
    gload16(ga0 + k0, la0);
    gload16(ga1 + k0, la1);
    gload16(gb0 + k0, lb0);
    gload16(gb1 + k0, lb1);
    __syncthreads();                 // vmcnt drained: LDS valid
    bf16x8 af[4], bfv[4];
    #pragma unroll
    for (int i = 0; i < 4; ++i) af[i]  = *(const bf16x8*)&As[(wm + i * 16 + fr) * 32 + q8];
    #pragma unroll
    for (int j = 0; j < 4; ++j) bfv[j] = *(const bf16x8*)&Bs[(wn + j * 16 + fr) * 32 + q8];
    #pragma unroll
    for (int i = 0; i < 4; ++i)
      #pragma unroll
      for (int j = 0; j < 4; ++j)
        acc[i][j] = __builtin_amdgcn_mfma_f32_16x16x32_bf16(af[i], bfv[j], acc[i][j], 0, 0, 0);
  }

  // D layout: row = (lane>>4)*4 + r, col = lane&15 (m89-verified)
  #pragma unroll
  for (int i = 0; i < 4; ++i){
    #pragma unroll
    for (int j = 0; j < 4; ++j){
      const int gr0 = bm * 128 + wm + i * 16 + ((lane >> 4) * 4);
      const int gc  = bn * 128 + wn + j * 16 + (lane & 15);
      const float bvv = bias[gc];
      #pragma unroll
      for (int r = 0; r < 4; ++r){
        const int gr = gr0 + r;
        const float val = (acc[i][j][r] + bvv) * scale;
        if (MODE == 0){
          const int b = gr >> 8, s = gr & 255, h = gc >> 6, kk = gc & 63;
          ((u16*)outp)[(size_t)wsel * 8388608 + (size_t)b * 262144 +
                       (size_t)h * 16384 + (size_t)s * 64 + kk] = f2bf(val);
        } else {
          ((float*)outp)[(size_t)gr * 1024 + gc] = val;
        }
      }
    }
  }
}

// ---------------- MFMA attention: block per (b,h) --------------------------
__global__ __launch_bounds__(256)
void attn_mfma(const u16* __restrict__ q, const u16* __restrict__ k,
               const u16* __restrict__ v, const float* __restrict__ divp,
               u16* __restrict__ attn_s)
{
  __shared__ u16 Vt[64][264];
  __shared__ u16 Ps[4][16][136];
  const int bh = blockIdx.x;
  const int b = bh >> 4, h = bh & 15;
  const int tid = threadIdx.x, lane = tid & 63, w = tid >> 6;
  const int quad = lane >> 4, l15 = lane & 15;
  const u16* kh = k + (size_t)bh * 16384;
  const u16* vh = v + (size_t)bh * 16384;
  const u16* qh = q + (size_t)bh * 16384;

  #pragma unroll
  for (int c = 0; c < 4; ++c){
    const int pidx = tid + c * 256;
    const int t2 = pidx & 127;
    const int n0 = (pidx >> 7) * 8;
    const uint4 a  = *(const uint4*)(vh + (2 * t2) * 64 + n0);
    const uint4 bb = *(const uint4*)(vh + (2 * t2 + 1) * 64 + n0);
    const u32 aa[4] = {a.x, a.y, a.z, a.w};
    const u32 bb4[4] = {bb.x, bb.y, bb.z, bb.w};
    #pragma unroll
    for (int j2 = 0; j2 < 4; ++j2){
      const u32 lo = aa[j2], hi = bb4[j2];
      *(u32*)&Vt[n0 + 2 * j2    ][2 * t2] = (lo & 0xffffu) | (hi << 16);
      *(u32*)&Vt[n0 + 2 * j2 + 1][2 * t2] = (lo >> 16) | (hi & 0xffff0000u);
    }
  }
  __syncthreads();

  const f32x4 z = {0.f, 0.f, 0.f, 0.f};
  const int bp = 2 * h + (b >> 4);
  for (int i = 0; i < 4; ++i){
    const int row0 = w * 64 + i * 16;
    const bf16x8 af0 = *(const bf16x8*)(qh + (size_t)(row0 + l15) * 64 + quad * 8);
    const bf16x8 af1 = *(const bf16x8*)(qh + (size_t)(row0 + l15) * 64 + 32 + quad * 8);
    f32x4 sc[16];
    #pragma unroll
    for (int ct = 0; ct < 16; ++ct){
      const bf16x8 b0 = *(const bf16x8*)(kh + (size_t)(ct * 16 + l15) * 64 + quad * 8);
      const bf16x8 b1 = *(const bf16x8*)(kh + (size_t)(ct * 16 + l15) * 64 + 32 + quad * 8);
      f32x4 a = __builtin_amdgcn_mfma_f32_16x16x32_bf16(af0, b0, z, 0, 0, 0);
      sc[ct]  = __builtin_amdgcn_mfma_f32_16x16x32_bf16(af1, b1, a, 0, 0, 0);
    }
    if (w == 0){
      const float* dv = divp + (size_t)b * 4096 + (size_t)(i * 16 + quad * 4) * 64 + l15;
      #pragma unroll
      for (int ct = 0; ct < 4; ++ct)
        #pragma unroll
        for (int rr = 0; rr < 4; ++rr)
          sc[ct][rr] += dv[rr * 64 + ct * 16];
    }
    float rs[4];
    #pragma unroll
    for (int rr = 0; rr < 4; ++rr){
      float m = sc[0][rr];
      #pragma unroll
      for (int ct = 1; ct < 16; ++ct) m = fmaxf(m, sc[ct][rr]);
      #pragma unroll
      for (int o = 1; o < 16; o <<= 1) m = fmaxf(m, __shfl_xor(m, o, 64));
      float s = 0.f;
      #pragma unroll
      for (int ct = 0; ct < 16; ++ct){
        const float e = __expf(sc[ct][rr] - m); sc[ct][rr] = e; s += e;
      }
      #pragma unroll
      for (int o = 1; o < 16; o <<= 1) s += __shfl_xor(s, o, 64);
      rs[rr] = 1.f / s;
    }
    f32x4 o4[4] = {z, z, z, z};
    #pragma unroll
    for (int half = 0; half < 2; ++half){
      #pragma unroll
      for (int ct = 0; ct < 8; ++ct)
        #pragma unroll
        for (int rr = 0; rr < 4; ++rr)
          Ps[w][quad * 4 + rr][ct * 16 + l15] = f2bf(sc[half * 8 + ct][rr] * rs[rr]);
      #pragma unroll
      for (int kc = 0; kc < 4; ++kc){
        const bf16x8 pa = *(const bf16x8*)&Ps[w][l15][kc * 32 + quad * 8];
        #pragma unroll
        for (int nt = 0; nt < 4; ++nt){
          const bf16x8 vb8 = *(const bf16x8*)&Vt[nt * 16 + l15][half * 128 + kc * 32 + quad * 8];
          o4[nt] = __builtin_amdgcn_mfma_f32_16x16x32_bf16(pa, vb8, o4[nt], 0, 0, 0);
        }
      }
    }
    const int sp = (b & 15) * 16 + (w * 4 + i);
    #pragma unroll
    for (int nt = 0; nt < 4; ++nt)
      #pragma unroll
      for (int rr = 0; rr < 4; ++rr){
        const int slo = quad * 4 + rr;
        const int cp = slo * 64 + nt * 16 + l15;
        attn_s[((size_t)bp * 256 + sp) * 1024 + cp] = f2bf(o4[nt][rr]);
      }
  }
}

// ---------------- attention_weights: mean over heads -----------------------
__global__ __launch_bounds__(256)
void aw_kernel(const u16* __restrict__ q, const u16* __restrict__ k,
               float* __restrict__ aw)
{
  __shared__ float redm[16][4];
  __shared__ float reds[16][4];
  const int blk = blockIdx.x;
  const int b = blk >> 4, st = blk & 15;
  const int tid = threadIdx.x, lane = tid & 63, w = tid >> 6;
  const int quad = lane >> 4, l15 = lane & 15;
  const int rowb = st * 16;
  const f32x4 z = {0.f, 0.f, 0.f, 0.f};
  float awacc[4][4] = {};
  for (int h = 0; h < 16; ++h){
    const u16* kh = k + (((size_t)b * 16 + h) * 16384);
    const u16* qh = q + (((size_t)b * 16 + h) * 16384);
    const bf16x8 af0 = *(const bf16x8*)(qh + (size_t)(rowb + l15) * 64 + quad * 8);
    const bf16x8 af1 = *(const bf16x8*)(qh + (size_t)(rowb + l15) * 64 + 32 + quad * 8);
    f32x4 sc[4];
    #pragma unroll
    for (int j4 = 0; j4 < 4; ++j4){
      const int ct = w * 4 + j4;
      const bf16x8 b0 = *(const bf16x8*)(kh + (size_t)(ct * 16 + l15) * 64 + quad * 8);
      const bf16x8 b1 = *(const bf16x8*)(kh + (size_t)(ct * 16 + l15) * 64 + 32 + quad * 8);
      f32x4 a = __builtin_amdgcn_mfma_f32_16x16x32_bf16(af0, b0, z, 0, 0, 0);
      sc[j4]  = __builtin_amdgcn_mfma_f32_16x16x32_bf16(af1, b1, a, 0, 0, 0);
    }
    float pm[4];
    #pragma unroll
    for (int rr = 0; rr < 4; ++rr){
      float m = fmaxf(fmaxf(sc[0][rr], sc[1][rr]), fmaxf(sc[2][rr], sc[3][rr]));
      #pragma unroll
      for (int o = 1; o < 16; o <<= 1) m = fmaxf(m, __shfl_xor(m, o, 64));
      pm[rr] = m;
    }
    if (l15 == 0)
      #pragma unroll
      for (int rr = 0; rr < 4; ++rr) redm[quad * 4 + rr][w] = pm[rr];
    __syncthreads();
    float ps[4];
    #pragma unroll
    for (int rr = 0; rr < 4; ++rr){
      const int row = quad * 4 + rr;
      const float m = fmaxf(fmaxf(redm[row][0], redm[row][1]),
                            fmaxf(redm[row][2], redm[row][3]));
      float s = 0.f;
      #pragma unroll
      for (int j4 = 0; j4 < 4; ++j4){
        const float e = __expf(sc[j4][rr] - m); sc[j4][rr] = e; s += e;
      }
      #pragma unroll
      for (int o = 1; o < 16; o <<= 1) s += __shfl_xor(s, o, 64);
      ps[rr] = s;
    }
    if (l15 == 0)
      #pragma unroll
      for (int rr = 0; rr < 4; ++rr) reds[quad * 4 + rr][w] = ps[rr];
    __syncthreads();
    #pragma unroll
    for (int rr = 0; rr < 4; ++rr){
      const int row = quad * 4 + rr;
      const float inv = 1.f / (reds[row][0] + reds[row][1] + reds[row][2] + reds[row][3]);
      #pragma unroll
      for (int j4 = 0; j4 < 4; ++j4) awacc[j4][rr] += sc[j4][rr] * inv;
    }
  }
  const size_t base = (size_t)b * 65536;
  #pragma unroll
  for (int j4 = 0; j4 < 4; ++j4){
    const int col = (w * 4 + j4) * 16 + l15;
    #pragma unroll
    for (int rr = 0; rr < 4; ++rr){
      const int row = rowb + quad * 4 + rr;
      aw[base + (size_t)row * 256 + col] = awacc[j4][rr] * 0.0625f;
    }
  }
}

// ---------------- residual + layernorm epilogue (fp32) ---------------------
__global__ __launch_bounds__(256)
void ln_kernel(const float* __restrict__ y2, const float* __restrict__ x,
               const float* __restrict__ g, const float* __restrict__ bb,
               float* __restrict__ outp)
{
  __shared__ float red[4];
  const int r = blockIdx.x, tid = threadIdx.x;
  const float4 yv = ((const float4*)(y2 + (size_t)r * 1024))[tid];
  const float4 xv = ((const float4*)(x  + (size_t)r * 1024))[tid];
  const float v0 = yv.x + xv.x;
  const float v1 = yv.y + xv.y;
  const float v2 = yv.z + xv.z;
  const float v3 = yv.w + xv.w;
  const float ssum = blockRed(v0 + v1 + v2 + v3, 0, red, tid);
  const float mu = ssum * (1.f / 1024.f);
  const float d0 = v0 - mu, d1 = v1 - mu, d2 = v2 - mu, d3 = v3 - mu;
  const float sq = blockRed(d0 * d0 + d1 * d1 + d2 * d2 + d3 * d3, 0, red, tid);
  const float rstd = rsqrtf(sq * (1.f / 1024.f) + 1e-5f);
  const float4 gv = ((const float4*)g)[tid];
  const float4 bv = ((const float4*)bb)[tid];
  float4 o;
  o.x = d0 * rstd * gv.x + bv.x;
  o.y = d1 * rstd * gv.y + bv.y;
  o.z = d2 * rstd * gv.z + bv.z;
  o.w = d3 * rstd * gv.w + bv.w;
  ((float4*)(outp + (size_t)r * 1024))[tid] = o;
}

extern "C" void kernel_launch(void* const* d_in, const int* in_sizes, int n_in,
                              void* d_out, int out_size, void* d_ws, size_t ws_size,
                              hipStream_t stream)
{
  int ix = -1, ipf = -1, iw[4] = {-1,-1,-1,-1}, iv[6] = {-1,-1,-1,-1,-1,-1};
  int nw = 0, nv = 0;
  for (int i = 0; i < n_in; ++i){
    const int sz = in_sizes[i];
    if (sz == 8388608 && ix < 0) ix = i;
    else if (sz == 262144 && ipf < 0) ipf = i;
    else if (sz == 1048576 && nw < 4) iw[nw++] = i;
    else if (sz == 1024 && nv < 6) iv[nv++] = i;
  }
  if (ix < 0 || ipf < 0 || nw != 4 || nv != 6){
    ix = 0; ipf = 1; iw[0] = 2; iv[0] = 3; iw[1] = 4; iv[1] = 5;
    iw[2] = 6; iv[2] = 7; iw[3] = 8; iv[3] = 9; iv[4] = 10; iv[5] = 11;
  }

  const float* x   = (const float*)d_in[ix];
  const float* pf  = (const float*)d_in[ipf];
  const float* wq  = (const float*)d_in[iw[0]];
  const float* wk  = (const float*)d_in[iw[1]];
  const float* wv  = (const float*)d_in[iw[2]];
  const float* wo  = (const float*)d_in[iw[3]];
  const float* bq  = (const float*)d_in[iv[0]];
  const float* bk  = (const float*)d_in[iv[1]];
  const float* bv  = (const float*)d_in[iv[2]];
  const float* bo  = (const float*)d_in[iv[3]];
  const float* lng = (const float*)d_in[iv[4]];
  const float* lnb = (const float*)d_in[iv[5]];

  float* out0   = (float*)d_out;            // final (B,H,W,d) fp32
  float* aw_out = out0 + 8388608;           // (B,S,S) fp32

  // d_out staging (dead before ln_kernel writes out0):
  //   [0, 16.78M)      x_bf bf16 (consumed by QKV gemm)
  //   [16.78M, 33.55M) attn scrambled bf16 (consumed by out-proj gemm)
  u16* x_bf = (u16*)d_out;
  u16* attn = x_bf + 8388608;
  // ws: qkv bf16 [0,48M); divp @48M (0.5M); W bf16 arena @49M (8MB);
  // y2 fp32 (32MB) aliases qkv after attention.
  u16* qkv    = (u16*)d_ws;
  float* divp = (float*)((char*)d_ws + (size_t)48 * 1048576);
  u16* warena = (u16*)((char*)d_ws + (size_t)49 * 1048576);
  float* y2   = (float*)d_ws;

  conv_x<<<4096, 256, 0, stream>>>(x, x_bf);
  conv_w4<<<dim3(512, 4), 256, 0, stream>>>(wq, wk, wv, wo, warena);
  div_kernel<<<32, 256, 0, stream>>>(pf, divp);

  gemm_lds<0><<<dim3(64, 24), 256, 0, stream>>>(x_bf, warena, bq, bk, bv, (void*)qkv);

  u16* qw = qkv, *kw = qkv + 8388608, *vw = qkv + 16777216;
  attn_mfma<<<512, 256, 0, stream>>>(qw, kw, vw, divp, attn);
  aw_kernel<<<512, 256, 0, stream>>>(qw, kw, aw_out);

  gemm_lds<1><<<dim3(64, 8), 256, 0, stream>>>(attn, warena + 3145728, bo, nullptr, nullptr, (void*)y2);
  ln_kernel<<<8192, 256, 0, stream>>>(y2, x, lng, lnb, out0);
}